// Round 3
// baseline (904.366 us; speedup 1.0000x reference)
//
#include <hip/hip_runtime.h>

// ---------------------------------------------------------------------------
// DecomposingAttnProcessor on MI355X (gfx950), all-bf16 MFMA pipeline.
// Stages: cvt(fp32->bf16) -> GEMM q/k/vT -> fused component-softmax attention
//         -> GEMM out (fp32).
// Big GEMMs (M=32768): 256x256 tile, BK=32, ring-4 LDS (128 KiB), REGISTER-
// PREFETCH software pipeline: ds_reads issued one half-tile ahead of their
// MFMA cluster (LDS pipe overlaps matrix pipe), counted lgkmcnt waits,
// 2 barriers/K-tile, counted vmcnt(8), setprio, XCD swizzle, chunk-XOR LDS
// swizzle. Small GEMMs (M=1232) keep the 128x128 kernel.
// ---------------------------------------------------------------------------

typedef unsigned short u16;
typedef unsigned int   u32;

#define NHS   50331648ULL   /* 8*4096*1536 */
#define NEHS  1892352ULL    /* 8*154*1536  */
#define NW    2359296ULL    /* 1536*1536   */
#define NVT   1966080ULL    /* 8*1536*160  */

using bf16x8 = __attribute__((ext_vector_type(8))) short;
using f32x4  = __attribute__((ext_vector_type(4))) float;

__device__ __forceinline__ u16 f2bf(float f) {
  union { float f; u32 u; } x{f};
  u32 r = (x.u + 0x7fffu + ((x.u >> 16) & 1u)) >> 16;   // RNE, inputs finite
  return (u16)r;
}

__device__ __forceinline__ void gload_lds16(const u16* g, u16* s) {
  // async global->LDS, 16B per lane; LDS dest = wave-uniform base + lane*16
  __builtin_amdgcn_global_load_lds((const __attribute__((address_space(1))) void*)g,
                                   (__attribute__((address_space(3))) void*)s,
                                   16, 0, 0);
}

#define WAITV(N) asm volatile("s_waitcnt vmcnt(" #N ")" ::: "memory")
#define LGKM(N)  do { asm volatile("s_waitcnt lgkmcnt(" #N ")" ::: "memory"); \
                      __builtin_amdgcn_sched_barrier(0); } while (0)

// ---------------------------------------------------------------------------
// fp32 -> bf16 elementwise conversion (vectorized float4 -> ushort4)
// ---------------------------------------------------------------------------
__global__ void cvt_bf16(const float* __restrict__ src, u16* __restrict__ dst, int n4) {
  int idx = blockIdx.x * blockDim.x + threadIdx.x;
  int stride = gridDim.x * blockDim.x;
  for (int i = idx; i < n4; i += stride) {
    float4 v = ((const float4*)src)[i];
    ushort4 o;
    o.x = f2bf(v.x); o.y = f2bf(v.y); o.z = f2bf(v.z); o.w = f2bf(v.w);
    ((ushort4*)dst)[i] = o;
  }
}

// ---------------------------------------------------------------------------
// BIG GEMM: C[32768,1536] = A[32768,1536]*Bw[1536,1536]^T + bias
// 256x256 tile, BK=32, 512 thr = 8 waves (2m x 4n), per-wave 128x64 out.
// Register-prefetch pipeline per K-tile t (2 half-tiles):
//  s1: issue afB(t) ds_reads + stage(t+3); lgkmcnt(4) [afA/bf ready];
//      16 MFMA (afA x bf)                 <- LDS serves afB under this
//  s2: vmcnt(8) [tile t+1 landed]; barrier;
//  s3: issue afA'/bf'(t+1) ds_reads; lgkmcnt(8) [afB ready];
//      16 MFMA (afB x bf); barrier        <- LDS serves next set under this
// Ping-pong register sets P/Q (tile parity), all-constant indexing.
// ---------------------------------------------------------------------------
template <int MODE>
__global__ __launch_bounds__(512, 2)
void gemm_big(const u16* __restrict__ Ag, const u16* __restrict__ Bw,
              const float* __restrict__ bias, void* __restrict__ Cv) {
  __shared__ __align__(16) u16 lds[65536];   // 128 KiB: 4 units x 16384 u16

  const int tid  = threadIdx.x;
  const int wv   = tid >> 6;
  const int lane = tid & 63;
  const int l16  = lane & 15, quad = lane >> 4;
  const int wm = wv >> 2, wn = wv & 3;       // 2 x 4 wave grid

  // XCD-bijective swizzle: 768 blocks, 96 per XCD, col-panel-major per XCD.
  const int wg = ((int)blockIdx.x & 7) * 96 + ((int)blockIdx.x >> 3);
  const int by = wg & 127;                   // row-block   (M/256 = 128)
  const int bx = wg >> 7;                    // col-block   (N/256 = 6)
  const int m0 = by * 256, n0 = bx * 256;

  // ---- loop-invariant stage addresses (4 gload_lds per thread per tile) ----
  const u16* gsrc[4];
#pragma unroll
  for (int q = 0; q < 4; ++q) {
    const int L = q * 512 + tid;
    const int cid = L & 1023;
    const int row = cid >> 2;
    const int csrc = ((L & 3) ^ ((row >> 1) & 3)) * 8;
    gsrc[q] = (L < 1024 ? Ag + (size_t)(m0 + row) * 1536
                        : Bw + (size_t)(n0 + row) * 1536) + csrc;
  }
  const int ldst0 = tid * 8;                 // LDS element offset; +q*4096

  // base swizzled read offsets; fragment i/j adds exact +i*512 elements
  // (swizzle term invariant under row+16/+64 steps), af high-half +2048.
  const int ra = wm * 128 + l16;
  const int aoff0 = ra * 32 + ((quad ^ ((ra >> 1) & 3)) * 8);
  const int rb = wn * 64 + l16;
  const int boff0 = 8192 + rb * 32 + ((quad ^ ((rb >> 1) & 3)) * 8);

  f32x4 acc[8][4];
#pragma unroll
  for (int i = 0; i < 8; ++i)
#pragma unroll
    for (int j = 0; j < 4; ++j) acc[i][j] = {0.f, 0.f, 0.f, 0.f};

  auto stage4 = [&](int tile) {
    u16* dst = &lds[(tile & 3) * 16384 + ldst0];
    const int kt = tile * 32;
    gload_lds16(gsrc[0] + kt, dst);
    gload_lds16(gsrc[1] + kt, dst + 4096);
    gload_lds16(gsrc[2] + kt, dst + 8192);
    gload_lds16(gsrc[3] + kt, dst + 12288);
  };

  bf16x8 afP[4], bfP[4], afQ[4], bfQ[4], afB[4];

#define LOADSET(AF, BF, T) {                                                  \
    const u16* u_ = &lds[((T) & 3) * 16384];                                  \
    _Pragma("unroll") for (int j = 0; j < 4; ++j)                             \
      BF[j] = *(const bf16x8*)(u_ + boff0 + j * 512);                         \
    _Pragma("unroll") for (int i = 0; i < 4; ++i)                             \
      AF[i] = *(const bf16x8*)(u_ + aoff0 + i * 512);                         \
  }
#define LOADAFB(T) {                                                          \
    const u16* u_ = &lds[((T) & 3) * 16384];                                  \
    _Pragma("unroll") for (int i = 0; i < 4; ++i)                             \
      afB[i] = *(const bf16x8*)(u_ + aoff0 + 2048 + i * 512);                 \
  }
#define MFMA16(AF, BF, BASE)                                                  \
    __builtin_amdgcn_s_setprio(1);                                            \
    _Pragma("unroll") for (int i = 0; i < 4; ++i)                             \
      _Pragma("unroll") for (int j = 0; j < 4; ++j)                           \
        acc[(BASE) + i][j] = __builtin_amdgcn_mfma_f32_16x16x32_bf16(         \
            AF[i], BF[j], acc[(BASE) + i][j], 0, 0, 0);                       \
    __builtin_amdgcn_s_setprio(0)

  // HALF1: issue afB(T) + stage(T+3); wait current set; MFMA low half.
#define HALF1(T, AF, BF, DOSTAGE)                                             \
    LOADAFB(T);                                                               \
    if (DOSTAGE) stage4((T) + 3);                                             \
    LGKM(4);                                                                  \
    MFMA16(AF, BF, 0)
  // HALF2: retire tile T+1; load next set from it; MFMA high half.
#define HALF2(T, AFN, BFN, BFCUR, WCODE)                                      \
    WCODE;                                                                    \
    __builtin_amdgcn_s_barrier();                                             \
    LOADSET(AFN, BFN, (T) + 1);                                               \
    LGKM(8);                                                                  \
    MFMA16(afB, BFCUR, 4);                                                    \
    __builtin_amdgcn_s_barrier()

  // ---- prologue: fill 3-deep staging pipeline, preload set P (tile 0) ----
  stage4(0); stage4(1); stage4(2);
  WAITV(8);                       // tile 0 landed; tiles 1,2 in flight
  __builtin_amdgcn_s_barrier();
  LOADSET(afP, bfP, 0);

  // ---- main loop: tiles 0..43 (unroll-2 ping-pong) ----
  for (int t = 0; t < 44; t += 2) {
    HALF1(t, afP, bfP, true);
    HALF2(t, afQ, bfQ, bfP, WAITV(8));
    HALF1(t + 1, afQ, bfQ, true);
    HALF2(t + 1, afP, bfP, bfQ, WAITV(8));
  }
  // ---- tail: tiles 44..47 ----
  HALF1(44, afP, bfP, true);               // stages tile 47 (last)
  HALF2(44, afQ, bfQ, bfP, WAITV(8));      // retires 45
  HALF1(45, afQ, bfQ, false);
  HALF2(45, afP, bfP, bfQ, WAITV(4));      // retires 46
  HALF1(46, afP, bfP, false);
  HALF2(46, afQ, bfQ, bfP, WAITV(0));      // retires 47
  LOADAFB(47);
  LGKM(4);
  MFMA16(afQ, bfQ, 0);
  LGKM(0);
  MFMA16(afB, bfQ, 4);

#undef HALF2
#undef HALF1
#undef MFMA16
#undef LOADAFB
#undef LOADSET

  // ---- epilogue: bias + store ----
#pragma unroll
  for (int i = 0; i < 8; ++i) {
    const int row0 = m0 + wm * 128 + i * 16 + quad * 4;
#pragma unroll
    for (int j = 0; j < 4; ++j) {
      const int col = n0 + wn * 64 + j * 16 + l16;
      const float bvs = bias[col];
#pragma unroll
      for (int rr = 0; rr < 4; ++rr) {
        const int row = row0 + rr;
        const float v = acc[i][j][rr] + bvs;
        if (MODE == 0) ((float*)Cv)[(size_t)row * 1536 + col] = v;
        else           ((u16*)Cv)[(size_t)row * 1536 + col] = f2bf(v);
      }
    }
  }
}

// ---------------------------------------------------------------------------
// Small GEMM (M=1232 K/V projections): 128x128 block tile, BK=32, 256 thr.
// MODE 1: bf16 out   MODE 2: bf16 out transposed for V (t padded to 160).
// ---------------------------------------------------------------------------
template <int MODE>
__global__ __launch_bounds__(256)
void gemm_bt(const u16* __restrict__ A, const u16* __restrict__ Bw,
             const float* __restrict__ bias, void* __restrict__ Cv,
             int M, int K) {
  const int N = 1536;
  __shared__ __align__(16) u16 As[4096];   // 128 rows x 32 (bf16)
  __shared__ __align__(16) u16 Bs[4096];
  const int tid  = threadIdx.x;
  const int wv   = tid >> 6;
  const int lane = tid & 63;
  const int wr = wv >> 1, wc = wv & 1;
  const int l16 = lane & 15, quad = lane >> 4;
  const int m0 = blockIdx.y * 128, n0 = blockIdx.x * 128;
  const int r = tid >> 2, c8 = (tid & 3) * 8;

  int ra0 = m0 + r;      if (ra0 > M - 1) ra0 = M - 1;   // M-edge clamp (loads)
  int ra1 = m0 + 64 + r; if (ra1 > M - 1) ra1 = M - 1;
  const u16* a0 = A  + (size_t)ra0 * K + c8;
  const u16* a1 = A  + (size_t)ra1 * K + c8;
  const u16* b0 = Bw + (size_t)(n0 + r) * K + c8;
  const u16* b1 = Bw + (size_t)(n0 + 64 + r) * K + c8;
  u16* asd0 = &As[tid * 8];
  u16* asd1 = &As[2048 + tid * 8];
  u16* bsd0 = &Bs[tid * 8];
  u16* bsd1 = &Bs[2048 + tid * 8];

  f32x4 acc[4][4];
#pragma unroll
  for (int i = 0; i < 4; ++i)
#pragma unroll
    for (int j = 0; j < 4; ++j) acc[i][j] = {0.f, 0.f, 0.f, 0.f};

  for (int kt = 0; kt < K; kt += 32) {
    __syncthreads();
    gload_lds16(a0 + kt, asd0);
    gload_lds16(a1 + kt, asd1);
    gload_lds16(b0 + kt, bsd0);
    gload_lds16(b1 + kt, bsd1);
    __syncthreads();
    bf16x8 af[4], bfr[4];
#pragma unroll
    for (int i = 0; i < 4; ++i) {
      af[i]  = *(const bf16x8*)&As[(wr * 64 + i * 16 + l16) * 32 + quad * 8];
      bfr[i] = *(const bf16x8*)&Bs[(wc * 64 + i * 16 + l16) * 32 + quad * 8];
    }
#pragma unroll
    for (int i = 0; i < 4; ++i)
#pragma unroll
      for (int j = 0; j < 4; ++j)
        acc[i][j] = __builtin_amdgcn_mfma_f32_16x16x32_bf16(af[i], bfr[j], acc[i][j], 0, 0, 0);
  }

#pragma unroll
  for (int i = 0; i < 4; ++i) {
    const int rb = m0 + wr * 64 + i * 16 + quad * 4;
#pragma unroll
    for (int j = 0; j < 4; ++j) {
      const int col = n0 + wc * 64 + j * 16 + l16;
      const float bvs = bias[col];
#pragma unroll
      for (int rr = 0; rr < 4; ++rr) {
        const int row = rb + rr;
        if (row < M) {
          float v = acc[i][j][rr] + bvs;
          if (MODE == 1) {
            ((u16*)Cv)[(size_t)row * N + col] = f2bf(v);
          } else {
            const int bc = row / 154;
            const int t  = row - bc * 154;
            ((u16*)Cv)[((size_t)bc * 1536 + col) * 160 + t] = f2bf(v);
          }
        }
      }
    }
  }
}

// ---------------------------------------------------------------------------
// Fused attention v2: component softmax + key renorm + PV, all MFMA.
// grid (64 s-tiles, 24 heads, 2 batches), 256 thr. Wave w owns s-rows
// [s0+16w, +16) for ALL 4 components -> softmax over c is in-register.
// ---------------------------------------------------------------------------
__global__ __launch_bounds__(256, 2)
void attn_kernel(const u16* __restrict__ qg, const u16* __restrict__ kg,
                 const u16* __restrict__ vtg, u16* __restrict__ og) {
  __shared__ __align__(16) u16 lds[40960];   // 80 KiB

  const int tid  = threadIdx.x;
  const int wv   = tid >> 6;
  const int lane = tid & 63;
  const int l16 = lane & 15, quad = lane >> 4;
  const int s0 = blockIdx.x * 64;
  const int h  = blockIdx.y;
  const int b  = blockIdx.z;
  const int swz = ((quad ^ ((l16 >> 1) & 3)) * 8);  // lane-const read swizzle (u16)

  // ---- stage K (async, 20 x 16B per thread), source-side chunk swizzle ----
  {
    const u16* kbase = kg + (size_t)b * 154 * 1536 + h * 64;
#pragma unroll
    for (int p = 0; p < 20; ++p) {
      const int L = p * 256 + tid;
      const int r = L >> 2;            // (c*2+ks)*160 + t
      const int t = r % 160;
      const int cks = r / 160;         // c*2+ks
      const int c = cks >> 1, ks = cks & 1;
      const int csrc = ((L & 3) ^ ((t >> 1) & 3)) * 8;
      const u16* src = kbase + ((size_t)c * 308 + t) * 1536 + ks * 32 + csrc;
      gload_lds16(src, &lds[(size_t)L * 8]);
    }
  }

  // ---- per-wave q A-fragments straight from global (16B contiguous) ----
  bf16x8 qa[4][2];
#pragma unroll
  for (int c = 0; c < 4; ++c) {
    const u16* qrow = qg + ((size_t)((c * 2 + b) * 4096 + s0 + wv * 16 + l16)) * 1536 + h * 64;
#pragma unroll
    for (int ks = 0; ks < 2; ++ks)
      qa[c][ks] = *(const bf16x8*)(qrow + ks * 32 + quad * 8);
  }
  __syncthreads();   // K staged (barrier drains vmcnt)

  // ---- scores: D[s][t] = q . k ----
  f32x4 sc[4][10];
#pragma unroll
  for (int c = 0; c < 4; ++c)
#pragma unroll
    for (int nt = 0; nt < 10; ++nt) sc[c][nt] = {0.f, 0.f, 0.f, 0.f};

#pragma unroll
  for (int nt = 0; nt < 10; ++nt)
#pragma unroll
    for (int c = 0; c < 4; ++c)
#pragma unroll
      for (int ks = 0; ks < 2; ++ks) {
        bf16x8 kf = *(const bf16x8*)&lds[((c * 2 + ks) * 160 + nt * 16 + l16) * 32 + swz];
        sc[c][nt] = __builtin_amdgcn_mfma_f32_16x16x32_bf16(qa[c][ks], kf, sc[c][nt], 0, 0, 0);
      }

  // ---- softmax over components (in-register) + t-row sums ----
  float rs[4][4];
#pragma unroll
  for (int c = 0; c < 4; ++c)
#pragma unroll
    for (int rr = 0; rr < 4; ++rr) rs[c][rr] = 0.f;

#pragma unroll
  for (int nt = 0; nt < 10; ++nt) {
    const int t = nt * 16 + l16;
    const bool ok = (t < 154);
#pragma unroll
    for (int rr = 0; rr < 4; ++rr) {
      float v0 = sc[0][nt][rr] * 0.125f;
      float v1 = sc[1][nt][rr] * 0.125f;
      float v2 = sc[2][nt][rr] * 0.125f;
      float v3 = sc[3][nt][rr] * 0.125f;
      float m = fmaxf(fmaxf(v0, v1), fmaxf(v2, v3));
      float e0 = __expf(v0 - m), e1 = __expf(v1 - m);
      float e2 = __expf(v2 - m), e3 = __expf(v3 - m);
      float inv = 1.f / (e0 + e1 + e2 + e3);
      float w0 = ok ? e0 * inv : 0.f;   // positional mask kills pad garbage/NaN
      float w1 = ok ? e1 * inv : 0.f;
      float w2 = ok ? e2 * inv : 0.f;
      float w3 = ok ? e3 * inv : 0.f;
      sc[0][nt][rr] = w0; sc[1][nt][rr] = w1; sc[2][nt][rr] = w2; sc[3][nt][rr] = w3;
      rs[0][rr] += w0; rs[1][rr] += w1; rs[2][rr] += w2; rs[3][rr] += w3;
    }
  }
#pragma unroll
  for (int c = 0; c < 4; ++c)
#pragma unroll
    for (int rr = 0; rr < 4; ++rr) {
      float v = rs[c][rr];
      v += __shfl_xor(v, 1); v += __shfl_xor(v, 2);
      v += __shfl_xor(v, 4); v += __shfl_xor(v, 8);
      rs[c][rr] = 1.f / (v + 1e-8f);
    }

  __syncthreads();   // all waves done reading K -> region reusable

  // ---- per-component pipelined PV over overlaid double-buffered slots ----
  const u16* vbase = vtg + ((size_t)b * 1536 + h * 64) * 160;

  auto stage_v = [&](int c, int par) {
    const u16* vb = vbase + (size_t)c * 2 * 1536 * 160;
    u16* slot = &lds[20480 + par * 10240];
#pragma unroll
    for (int p = 0; p < 5; ++p) {
      const int L = p * 256 + tid;
      const int row = L >> 2;          // ks*64 + dh
      const int ks = row >> 6, dh = row & 63;
      const int csrc = ((L & 3) ^ ((dh >> 1) & 3)) * 8;
      gload_lds16(vb + dh * 160 + ks * 32 + csrc, &slot[(size_t)L * 8]);
    }
  };

  auto write_w = [&](int c, int par) {
    u16* slot = &lds[par * 10240];
#pragma unroll
    for (int nt = 0; nt < 10; ++nt) {
#pragma unroll
      for (int rr = 0; rr < 4; ++rr) {
        const int srow = wv * 16 + quad * 4 + rr;
        const int t = nt * 16 + l16;
        const int cl = ((t >> 3) & 3) ^ ((srow >> 1) & 3);
        slot[srow * 160 + (t >> 5) * 32 + cl * 8 + (t & 7)] =
            f2bf(sc[c][nt][rr] * rs[c][rr]);
      }
    }
  };

  f32x4 oacc[4][4];
#pragma unroll
  for (int c = 0; c < 4; ++c)
#pragma unroll
    for (int nd = 0; nd < 4; ++nd) oacc[c][nd] = {0.f, 0.f, 0.f, 0.f};

  stage_v(0, 0);
  write_w(0, 0);
#pragma unroll
  for (int c = 0; c < 4; ++c) {
    __syncthreads();                 // V_c arrived; slot[(c+1)&1] free
    if (c < 3) { stage_v(c + 1, (c + 1) & 1); write_w(c + 1, (c + 1) & 1); }
    const int par = c & 1;
    const u16* sw = &lds[par * 10240];
    const u16* sv = &lds[20480 + par * 10240];
#pragma unroll
    for (int ks = 0; ks < 5; ++ks) {
      bf16x8 wa = *(const bf16x8*)&sw[(wv * 16 + l16) * 160 + ks * 32 + swz];
#pragma unroll
      for (int nd = 0; nd < 4; ++nd) {
        bf16x8 vf = *(const bf16x8*)&sv[(ks * 64 + nd * 16 + l16) * 32 + swz];
        oacc[c][nd] = __builtin_amdgcn_mfma_f32_16x16x32_bf16(wa, vf, oacc[c][nd], 0, 0, 0);
      }
    }
  }

  // ---- store attention output (bf16, head-major D layout) ----
#pragma unroll
  for (int c = 0; c < 4; ++c)
#pragma unroll
    for (int nd = 0; nd < 4; ++nd)
#pragma unroll
      for (int rr = 0; rr < 4; ++rr) {
        const int srow = s0 + wv * 16 + quad * 4 + rr;
        og[((size_t)((c * 2 + b) * 4096 + srow)) * 1536 + h * 64 + nd * 16 + l16] =
            f2bf(oacc[c][nd][rr]);
      }
}

// ---------------------------------------------------------------------------
extern "C" void kernel_launch(void* const* d_in, const int* in_sizes, int n_in,
                              void* d_out, int out_size, void* d_ws, size_t ws_size,
                              hipStream_t stream) {
  (void)in_sizes; (void)n_in; (void)out_size; (void)ws_size;
  const float* hs  = (const float*)d_in[0];
  const float* ehs = (const float*)d_in[1];
  const float* Wq  = (const float*)d_in[2];
  const float* bq  = (const float*)d_in[3];
  const float* Wk  = (const float*)d_in[4];
  const float* bk  = (const float*)d_in[5];
  const float* Wv  = (const float*)d_in[6];
  const float* bv  = (const float*)d_in[7];
  const float* Wo  = (const float*)d_in[8];
  const float* bo  = (const float*)d_in[9];
  float* out = (float*)d_out;

  u16* ws   = (u16*)d_ws;
  u16* hsb  = ws;               // [8*4096, 1536] bf16
  u16* ehsb = hsb + NHS;        // [8*154, 1536]  bf16
  u16* wqb  = ehsb + NEHS;
  u16* wkb  = wqb + NW;
  u16* wvb  = wkb + NW;
  u16* wob  = wvb + NW;
  u16* qb   = wob + NW;         // q  [8*4096, 1536] bf16
  u16* kgb  = qb + NHS;         // k  [8*154, 1536]  bf16
  u16* vtb  = kgb + NEHS;       // v^T [8][1536][160] bf16
  u16* atb  = vtb + NVT;        // attn out [8*4096, 1536] bf16

  auto cvt = [&](const float* s, u16* d, size_t n) {
    int n4 = (int)(n / 4);
    int blocks = (n4 + 255) / 256;
    if (blocks > 8192) blocks = 8192;
    cvt_bf16<<<blocks, 256, 0, stream>>>(s, d, n4);
  };
  cvt(hs, hsb, NHS);
  cvt(ehs, ehsb, NEHS);
  cvt(Wq, wqb, NW);
  cvt(Wk, wkb, NW);
  cvt(Wv, wvb, NW);
  cvt(Wo, wob, NW);

  gemm_big<1><<<dim3(768), 512, 0, stream>>>(hsb, wqb, bq, qb);
  gemm_bt<1><<<dim3(12, 10), 256, 0, stream>>>(ehsb, wkb, bk, kgb, 1232, 1536);
  gemm_bt<2><<<dim3(12, 10), 256, 0, stream>>>(ehsb, wvb, bv, vtb, 1232, 1536);

  attn_kernel<<<dim3(64, 24, 2), 256, 0, stream>>>(qb, kgb, vtb, atb);

  gemm_big<0><<<dim3(768), 512, 0, stream>>>(atb, wob, bo, out);
}

// Round 5
// 883.640 us; speedup vs baseline: 1.0235x; 1.0235x over previous
//
#include <hip/hip_runtime.h>

// ---------------------------------------------------------------------------
// DecomposingAttnProcessor on MI355X (gfx950), all-bf16 MFMA pipeline.
// Stages: cvt(fp32->bf16) -> GEMM q/k/vT -> fused component-softmax attention
//         -> GEMM out (fp32).
// Big GEMMs (M=32768): m201-geometry 256x256 tile, BK=64, ring-2 LDS
// (2 x 64KB), 8 waves (2Mx4N), 4 balanced phases per K-tile:
//   ph(ks,rh) = {4-8 ds_reads + 16KB stage unit; barrier; lgkmcnt(0);
//                setprio(1); 16 MFMA; setprio(0); barrier}
// vmcnt(0) only at tile boundary (loads then 3-4 phases old -> no stall).
// BK=64 rows = 128B -> full-cache-line staging. 3-bit chunk-XOR swizzle.
// Small GEMMs (M=1232) keep the 128x128 kernel.
// (Resubmission of round-4 source: bench failed infra-side; kernel audited
// for deadlock/OOB/WAR races — none found.)
// ---------------------------------------------------------------------------

typedef unsigned short u16;
typedef unsigned int   u32;

#define NHS   50331648ULL   /* 8*4096*1536 */
#define NEHS  1892352ULL    /* 8*154*1536  */
#define NW    2359296ULL    /* 1536*1536   */
#define NVT   1966080ULL    /* 8*1536*160  */

using bf16x8 = __attribute__((ext_vector_type(8))) short;
using f32x4  = __attribute__((ext_vector_type(4))) float;

__device__ __forceinline__ u16 f2bf(float f) {
  union { float f; u32 u; } x{f};
  u32 r = (x.u + 0x7fffu + ((x.u >> 16) & 1u)) >> 16;   // RNE, inputs finite
  return (u16)r;
}

__device__ __forceinline__ void gload_lds16(const u16* g, u16* s) {
  // async global->LDS, 16B per lane; LDS dest = wave-uniform base + lane*16
  __builtin_amdgcn_global_load_lds((const __attribute__((address_space(1))) void*)g,
                                   (__attribute__((address_space(3))) void*)s,
                                   16, 0, 0);
}

#define WAITV(N) asm volatile("s_waitcnt vmcnt(" #N ")" ::: "memory")
#define LGKM(N)  do { asm volatile("s_waitcnt lgkmcnt(" #N ")" ::: "memory"); \
                      __builtin_amdgcn_sched_barrier(0); } while (0)

// ---------------------------------------------------------------------------
// fp32 -> bf16 elementwise conversion (vectorized float4 -> ushort4)
// ---------------------------------------------------------------------------
__global__ void cvt_bf16(const float* __restrict__ src, u16* __restrict__ dst, int n4) {
  int idx = blockIdx.x * blockDim.x + threadIdx.x;
  int stride = gridDim.x * blockDim.x;
  for (int i = idx; i < n4; i += stride) {
    float4 v = ((const float4*)src)[i];
    ushort4 o;
    o.x = f2bf(v.x); o.y = f2bf(v.y); o.z = f2bf(v.z); o.w = f2bf(v.w);
    ((ushort4*)dst)[i] = o;
  }
}

// ---------------------------------------------------------------------------
// BIG GEMM: C[32768,1536] = A[32768,1536]*Bw[1536,1536]^T + bias
// 256x256 tile, BK=64, 512 thr = 8 waves (2m x 4n), wave tile 128x64.
// LDS: 2 bufs x (A[256][64] + B[256][64]) = 2 x 64KB. 24 K-tiles.
// Per tile: 4 phases (ks0/rh0, ks0/rh1, ks1/rh0, ks1/rh1), 16 MFMA each.
// Stage tile T+1 (A in ph0, B in ph1) into the other buffer; WAITV(0) at
// tile end (loads are 3-4 phases old). Chunk-XOR swizzle: physical chunk =
// logical_k_chunk ^ (row&7), applied on global source + ds_read offset.
// MODE 0: fp32 out.  MODE 1: bf16 out.
// ---------------------------------------------------------------------------
template <int MODE>
__global__ __launch_bounds__(512, 2)
void gemm_big(const u16* __restrict__ Ag, const u16* __restrict__ Bw,
              const float* __restrict__ bias, void* __restrict__ Cv) {
  __shared__ __align__(16) u16 lds[65536];   // 128 KiB: 2 bufs x 32768 u16

  const int tid  = threadIdx.x;
  const int wv   = tid >> 6;
  const int lane = tid & 63;
  const int l16  = lane & 15, quad = lane >> 4;
  const int wm = wv >> 2, wn = wv & 3;       // 2 x 4 wave grid

  // XCD-bijective swizzle: 768 blocks, 96 per XCD.
  const int wg = ((int)blockIdx.x & 7) * 96 + ((int)blockIdx.x >> 3);
  const int by = wg & 127;                   // row-block (M/256 = 128)
  const int bx = wg >> 7;                    // col-block (N/256 = 6)
  const int m0 = by * 256, n0 = bx * 256;

  // ---- stage source offsets: chunk c = i*512+tid, row=c>>3, 8 chunks/row ----
  // physical chunk c holds logical k-chunk (c&7)^(row&7) -> source offset:
  int soff[4];
#pragma unroll
  for (int i = 0; i < 4; ++i) {
    const int c = i * 512 + tid;
    const int row = c >> 3;
    soff[i] = row * 1536 + (((c & 7) ^ (row & 7)) * 8);
  }
  const u16* Abp = Ag + (size_t)m0 * 1536;
  const u16* Bbp = Bw + (size_t)n0 * 1536;
  const int ldst = tid * 8;                  // + i*4096 per load

  // ---- swizzled read offsets (row&7 == l16&7 for all fragments) ----
  int aoffb[2], boffb[2];
#pragma unroll
  for (int ks = 0; ks < 2; ++ks) {
    const int ch = ((ks * 4 + quad) ^ (l16 & 7)) * 8;
    aoffb[ks] = (wm * 128 + l16) * 64 + ch;
    boffb[ks] = 16384 + (wn * 64 + l16) * 64 + ch;
  }

  f32x4 acc[8][4];
#pragma unroll
  for (int i = 0; i < 8; ++i)
#pragma unroll
    for (int j = 0; j < 4; ++j) acc[i][j] = {0.f, 0.f, 0.f, 0.f};

  bf16x8 af[4], bf[4];

#define STG_A(TN, BN) do {                                                    \
    gload_lds16(Abp + soff[0] + (TN) * 64, &lds[(BN) + ldst]);                \
    gload_lds16(Abp + soff[1] + (TN) * 64, &lds[(BN) + 4096 + ldst]);         \
    gload_lds16(Abp + soff[2] + (TN) * 64, &lds[(BN) + 8192 + ldst]);         \
    gload_lds16(Abp + soff[3] + (TN) * 64, &lds[(BN) + 12288 + ldst]);        \
  } while (0)
#define STG_B(TN, BN) do {                                                    \
    gload_lds16(Bbp + soff[0] + (TN) * 64, &lds[(BN) + 16384 + ldst]);        \
    gload_lds16(Bbp + soff[1] + (TN) * 64, &lds[(BN) + 20480 + ldst]);        \
    gload_lds16(Bbp + soff[2] + (TN) * 64, &lds[(BN) + 24576 + ldst]);        \
    gload_lds16(Bbp + soff[3] + (TN) * 64, &lds[(BN) + 28672 + ldst]);        \
  } while (0)
#define RD_AF(BC, KS, RH)                                                     \
    _Pragma("unroll") for (int i = 0; i < 4; ++i)                             \
      af[i] = *(const bf16x8*)&lds[(BC) + aoffb[KS] + (RH) * 4096 + i * 1024]
#define RD_BF(BC, KS)                                                         \
    _Pragma("unroll") for (int j = 0; j < 4; ++j)                             \
      bf[j] = *(const bf16x8*)&lds[(BC) + boffb[KS] + j * 1024]
#define MM16(RH)                                                              \
    __builtin_amdgcn_s_setprio(1);                                            \
    _Pragma("unroll") for (int i = 0; i < 4; ++i)                             \
      _Pragma("unroll") for (int j = 0; j < 4; ++j)                           \
        acc[(RH) * 4 + i][j] = __builtin_amdgcn_mfma_f32_16x16x32_bf16(       \
            af[i], bf[j], acc[(RH) * 4 + i][j], 0, 0, 0);                     \
    __builtin_amdgcn_s_setprio(0)
#define BAR __builtin_amdgcn_s_barrier()

  // 4 phases per tile; stage A(T+1) in ph0, B(T+1) in ph1; WAITV(0) at end.
#define TILE(BC, BN, TN, DOST, DOWAIT) do {                                   \
    /* ph0: ks0, rh0 */                                                       \
    RD_BF(BC, 0); RD_AF(BC, 0, 0);                                            \
    if (DOST) STG_A(TN, BN);                                                  \
    BAR; LGKM(0); MM16(0); BAR;                                               \
    /* ph1: ks0, rh1 */                                                       \
    RD_AF(BC, 0, 1);                                                          \
    if (DOST) STG_B(TN, BN);                                                  \
    BAR; LGKM(0); MM16(1); BAR;                                               \
    /* ph2: ks1, rh0 */                                                       \
    RD_BF(BC, 1); RD_AF(BC, 1, 0);                                            \
    BAR; LGKM(0); MM16(0); BAR;                                               \
    /* ph3: ks1, rh1 */                                                       \
    RD_AF(BC, 1, 1);                                                          \
    BAR; LGKM(0); MM16(1);                                                    \
    if (DOWAIT) WAITV(0);                                                     \
    BAR;                                                                      \
  } while (0)

  // ---- prologue: stage tile 0 into buf0 ----
  STG_A(0, 0); STG_B(0, 0);
  WAITV(0);
  BAR;

  // ---- main loop: 24 K-tiles, ping-pong buffers ----
  for (int t = 0; t < 22; t += 2) {
    TILE(0,     32768, t + 1, true, true);
    TILE(32768, 0,     t + 2, true, true);
  }
  TILE(0,     32768, 23, true, true);    // tile 22, stages 23
  TILE(32768, 0,     24, false, false);  // tile 23, no stage

#undef TILE
#undef BAR
#undef MM16
#undef RD_BF
#undef RD_AF
#undef STG_B
#undef STG_A

  // ---- epilogue: bias + store ----
#pragma unroll
  for (int i = 0; i < 8; ++i) {
    const int row0 = m0 + wm * 128 + i * 16 + quad * 4;
#pragma unroll
    for (int j = 0; j < 4; ++j) {
      const int col = n0 + wn * 64 + j * 16 + l16;
      const float bvs = bias[col];
#pragma unroll
      for (int rr = 0; rr < 4; ++rr) {
        const int row = row0 + rr;
        const float v = acc[i][j][rr] + bvs;
        if (MODE == 0) ((float*)Cv)[(size_t)row * 1536 + col] = v;
        else           ((u16*)Cv)[(size_t)row * 1536 + col] = f2bf(v);
      }
    }
  }
}

// ---------------------------------------------------------------------------
// Small GEMM (M=1232 K/V projections): 128x128 block tile, BK=32, 256 thr.
// MODE 1: bf16 out   MODE 2: bf16 out transposed for V (t padded to 160).
// ---------------------------------------------------------------------------
template <int MODE>
__global__ __launch_bounds__(256)
void gemm_bt(const u16* __restrict__ A, const u16* __restrict__ Bw,
             const float* __restrict__ bias, void* __restrict__ Cv,
             int M, int K) {
  const int N = 1536;
  __shared__ __align__(16) u16 As[4096];   // 128 rows x 32 (bf16)
  __shared__ __align__(16) u16 Bs[4096];
  const int tid  = threadIdx.x;
  const int wv   = tid >> 6;
  const int lane = tid & 63;
  const int wr = wv >> 1, wc = wv & 1;
  const int l16 = lane & 15, quad = lane >> 4;
  const int m0 = blockIdx.y * 128, n0 = blockIdx.x * 128;
  const int r = tid >> 2, c8 = (tid & 3) * 8;

  int ra0 = m0 + r;      if (ra0 > M - 1) ra0 = M - 1;   // M-edge clamp (loads)
  int ra1 = m0 + 64 + r; if (ra1 > M - 1) ra1 = M - 1;
  const u16* a0 = A  + (size_t)ra0 * K + c8;
  const u16* a1 = A  + (size_t)ra1 * K + c8;
  const u16* b0 = Bw + (size_t)(n0 + r) * K + c8;
  const u16* b1 = Bw + (size_t)(n0 + 64 + r) * K + c8;
  u16* asd0 = &As[tid * 8];
  u16* asd1 = &As[2048 + tid * 8];
  u16* bsd0 = &Bs[tid * 8];
  u16* bsd1 = &Bs[2048 + tid * 8];

  f32x4 acc[4][4];
#pragma unroll
  for (int i = 0; i < 4; ++i)
#pragma unroll
    for (int j = 0; j < 4; ++j) acc[i][j] = {0.f, 0.f, 0.f, 0.f};

  for (int kt = 0; kt < K; kt += 32) {
    __syncthreads();
    gload_lds16(a0 + kt, asd0);
    gload_lds16(a1 + kt, asd1);
    gload_lds16(b0 + kt, bsd0);
    gload_lds16(b1 + kt, bsd1);
    __syncthreads();
    bf16x8 af[4], bfr[4];
#pragma unroll
    for (int i = 0; i < 4; ++i) {
      af[i]  = *(const bf16x8*)&As[(wr * 64 + i * 16 + l16) * 32 + quad * 8];
      bfr[i] = *(const bf16x8*)&Bs[(wc * 64 + i * 16 + l16) * 32 + quad * 8];
    }
#pragma unroll
    for (int i = 0; i < 4; ++i)
#pragma unroll
      for (int j = 0; j < 4; ++j)
        acc[i][j] = __builtin_amdgcn_mfma_f32_16x16x32_bf16(af[i], bfr[j], acc[i][j], 0, 0, 0);
  }

#pragma unroll
  for (int i = 0; i < 4; ++i) {
    const int rb = m0 + wr * 64 + i * 16 + quad * 4;
#pragma unroll
    for (int j = 0; j < 4; ++j) {
      const int col = n0 + wc * 64 + j * 16 + l16;
      const float bvs = bias[col];
#pragma unroll
      for (int rr = 0; rr < 4; ++rr) {
        const int row = rb + rr;
        if (row < M) {
          float v = acc[i][j][rr] + bvs;
          if (MODE == 1) {
            ((u16*)Cv)[(size_t)row * N + col] = f2bf(v);
          } else {
            const int bc = row / 154;
            const int t  = row - bc * 154;
            ((u16*)Cv)[((size_t)bc * 1536 + col) * 160 + t] = f2bf(v);
          }
        }
      }
    }
  }
}

// ---------------------------------------------------------------------------
// Fused attention v2: component softmax + key renorm + PV, all MFMA.
// grid (64 s-tiles, 24 heads, 2 batches), 256 thr. Wave w owns s-rows
// [s0+16w, +16) for ALL 4 components -> softmax over c is in-register.
// ---------------------------------------------------------------------------
__global__ __launch_bounds__(256, 2)
void attn_kernel(const u16* __restrict__ qg, const u16* __restrict__ kg,
                 const u16* __restrict__ vtg, u16* __restrict__ og) {
  __shared__ __align__(16) u16 lds[40960];   // 80 KiB

  const int tid  = threadIdx.x;
  const int wv   = tid >> 6;
  const int lane = tid & 63;
  const int l16 = lane & 15, quad = lane >> 4;
  const int s0 = blockIdx.x * 64;
  const int h  = blockIdx.y;
  const int b  = blockIdx.z;
  const int swz = ((quad ^ ((l16 >> 1) & 3)) * 8);  // lane-const read swizzle (u16)

  // ---- stage K (async, 20 x 16B per thread), source-side chunk swizzle ----
  {
    const u16* kbase = kg + (size_t)b * 154 * 1536 + h * 64;
#pragma unroll
    for (int p = 0; p < 20; ++p) {
      const int L = p * 256 + tid;
      const int r = L >> 2;            // (c*2+ks)*160 + t
      const int t = r % 160;
      const int cks = r / 160;         // c*2+ks
      const int c = cks >> 1, ks = cks & 1;
      const int csrc = ((L & 3) ^ ((t >> 1) & 3)) * 8;
      const u16* src = kbase + ((size_t)c * 308 + t) * 1536 + ks * 32 + csrc;
      gload_lds16(src, &lds[(size_t)L * 8]);
    }
  }

  // ---- per-wave q A-fragments straight from global (16B contiguous) ----
  bf16x8 qa[4][2];
#pragma unroll
  for (int c = 0; c < 4; ++c) {
    const u16* qrow = qg + ((size_t)((c * 2 + b) * 4096 + s0 + wv * 16 + l16)) * 1536 + h * 64;
#pragma unroll
    for (int ks = 0; ks < 2; ++ks)
      qa[c][ks] = *(const bf16x8*)(qrow + ks * 32 + quad * 8);
  }
  __syncthreads();   // K staged (barrier drains vmcnt)

  // ---- scores: D[s][t] = q . k ----
  f32x4 sc[4][10];
#pragma unroll
  for (int c = 0; c < 4; ++c)
#pragma unroll
    for (int nt = 0; nt < 10; ++nt) sc[c][nt] = {0.f, 0.f, 0.f, 0.f};

#pragma unroll
  for (int nt = 0; nt < 10; ++nt)
#pragma unroll
    for (int c = 0; c < 4; ++c)
#pragma unroll
      for (int ks = 0; ks < 2; ++ks) {
        bf16x8 kf = *(const bf16x8*)&lds[((c * 2 + ks) * 160 + nt * 16 + l16) * 32 + swz];
        sc[c][nt] = __builtin_amdgcn_mfma_f32_16x16x32_bf16(qa[c][ks], kf, sc[c][nt], 0, 0, 0);
      }

  // ---- softmax over components (in-register) + t-row sums ----
  float rs[4][4];
#pragma unroll
  for (int c = 0; c < 4; ++c)
#pragma unroll
    for (int rr = 0; rr < 4; ++rr) rs[c][rr] = 0.f;

#pragma unroll
  for (int nt = 0; nt < 10; ++nt) {
    const int t = nt * 16 + l16;
    const bool ok = (t < 154);
#pragma unroll
    for (int rr = 0; rr < 4; ++rr) {
      float v0 = sc[0][nt][rr] * 0.125f;
      float v1 = sc[1][nt][rr] * 0.125f;
      float v2 = sc[2][nt][rr] * 0.125f;
      float v3 = sc[3][nt][rr] * 0.125f;
      float m = fmaxf(fmaxf(v0, v1), fmaxf(v2, v3));
      float e0 = __expf(v0 - m), e1 = __expf(v1 - m);
      float e2 = __expf(v2 - m), e3 = __expf(v3 - m);
      float inv = 1.f / (e0 + e1 + e2 + e3);
      float w0 = ok ? e0 * inv : 0.f;   // positional mask kills pad garbage/NaN
      float w1 = ok ? e1 * inv : 0.f;
      float w2 = ok ? e2 * inv : 0.f;
      float w3 = ok ? e3 * inv : 0.f;
      sc[0][nt][rr] = w0; sc[1][nt][rr] = w1; sc[2][nt][rr] = w2; sc[3][nt][rr] = w3;
      rs[0][rr] += w0; rs[1][rr] += w1; rs[2][rr] += w2; rs[3][rr] += w3;
    }
  }
#pragma unroll
  for (int c = 0; c < 4; ++c)
#pragma unroll
    for (int rr = 0; rr < 4; ++rr) {
      float v = rs[c][rr];
      v += __shfl_xor(v, 1); v += __shfl_xor(v, 2);
      v += __shfl_xor(v, 4); v += __shfl_xor(v, 8);
      rs[c][rr] = 1.f / (v + 1e-8f);
    }

  __syncthreads();   // all waves done reading K -> region reusable

  // ---- per-component pipelined PV over overlaid double-buffered slots ----
  const u16* vbase = vtg + ((size_t)b * 1536 + h * 64) * 160;

  auto stage_v = [&](int c, int par) {
    const u16* vb = vbase + (size_t)c * 2 * 1536 * 160;
    u16* slot = &lds[20480 + par * 10240];
#pragma unroll
    for (int p = 0; p < 5; ++p) {
      const int L = p * 256 + tid;
      const int row = L >> 2;          // ks*64 + dh
      const int ks = row >> 6, dh = row & 63;
      const int csrc = ((L & 3) ^ ((dh >> 1) & 3)) * 8;
      gload_lds16(vb + dh * 160 + ks * 32 + csrc, &slot[(size_t)L * 8]);
    }
  };

  auto write_w = [&](int c, int par) {
    u16* slot = &lds[par * 10240];
#pragma unroll
    for (int nt = 0; nt < 10; ++nt) {
#pragma unroll
      for (int rr = 0; rr < 4; ++rr) {
        const int srow = wv * 16 + quad * 4 + rr;
        const int t = nt * 16 + l16;
        const int cl = ((t >> 3) & 3) ^ ((srow >> 1) & 3);
        slot[srow * 160 + (t >> 5) * 32 + cl * 8 + (t & 7)] =
            f2bf(sc[c][nt][rr] * rs[c][rr]);
      }
    }
  };

  f32x4 oacc[4][4];
#pragma unroll
  for (int c = 0; c < 4; ++c)
#pragma unroll
    for (int nd = 0; nd < 4; ++nd) oacc[c][nd] = {0.f, 0.f, 0.f, 0.f};

  stage_v(0, 0);
  write_w(0, 0);
#pragma unroll
  for (int c = 0; c < 4; ++c) {
    __syncthreads();                 // V_c arrived; slot[(c+1)&1] free
    if (c < 3) { stage_v(c + 1, (c + 1) & 1); write_w(c + 1, (c + 1) & 1); }
    const int par = c & 1;
    const u16* sw = &lds[par * 10240];
    const u16* sv = &lds[20480 + par * 10240];
#pragma unroll
    for (int ks = 0; ks < 5; ++ks) {
      bf16x8 wa = *(const bf16x8*)&sw[(wv * 16 + l16) * 160 + ks * 32 + swz];
#pragma unroll
      for (int nd = 0; nd < 4; ++nd) {
        bf16x8 vf = *(const bf16x8*)&sv[(ks * 64 + nd * 16 + l16) * 32 + swz];
        oacc[c][nd] = __builtin_amdgcn_mfma_f32_16x16x32_bf16(wa, vf, oacc[c][nd], 0, 0, 0);
      }
    }
  }

  // ---- store attention output (bf16, head-major D layout) ----
#pragma unroll
  for (int c = 0; c < 4; ++c)
#pragma unroll
    for (int nd = 0; nd < 4; ++nd)
#pragma unroll
      for (int rr = 0; rr < 4; ++rr) {
        const int srow = s0 + wv * 16 + quad * 4 + rr;
        og[((size_t)((c * 2 + b) * 4096 + srow)) * 1536 + h * 64 + nd * 16 + l16] =
            f2bf(oacc[c][nd][rr]);
      }
}

// ---------------------------------------------------------------------------
extern "C" void kernel_launch(void* const* d_in, const int* in_sizes, int n_in,
                              void* d_out, int out_size, void* d_ws, size_t ws_size,
                              hipStream_t stream) {
  (void)in_sizes; (void)n_in; (void)out_size; (void)ws_size;
  const float* hs  = (const float*)d_in[0];
  const float* ehs = (const float*)d_in[1];
  const float* Wq  = (const float*)d_in[2];
  const float* bq  = (const float*)d_in[3];
  const float* Wk  = (const float*)d_in[4];
  const float* bk  = (const float*)d_in[5];
  const float* Wv  = (const float*)d_in[6];
  const float* bv  = (const float*)d_in[7];
  const float* Wo  = (const float*)d_in[8];
  const float* bo  = (const float*)d_in[9];
  float* out = (float*)d_out;

  u16* ws   = (u16*)d_ws;
  u16* hsb  = ws;               // [8*4096, 1536] bf16
  u16* ehsb = hsb + NHS;        // [8*154, 1536]  bf16
  u16* wqb  = ehsb + NEHS;
  u16* wkb  = wqb + NW;
  u16* wvb  = wkb + NW;
  u16* wob  = wvb + NW;
  u16* qb   = wob + NW;         // q  [8*4096, 1536] bf16
  u16* kgb  = qb + NHS;         // k  [8*154, 1536]  bf16
  u16* vtb  = kgb + NEHS;       // v^T [8][1536][160] bf16
  u16* atb  = vtb + NVT;        // attn out [8*4096, 1536] bf16

  auto cvt = [&](const float* s, u16* d, size_t n) {
    int n4 = (int)(n / 4);
    int blocks = (n4 + 255) / 256;
    if (blocks > 8192) blocks = 8192;
    cvt_bf16<<<blocks, 256, 0, stream>>>(s, d, n4);
  };
  cvt(hs, hsb, NHS);
  cvt(ehs, ehsb, NEHS);
  cvt(Wq, wqb, NW);
  cvt(Wk, wkb, NW);
  cvt(Wv, wvb, NW);
  cvt(Wo, wob, NW);

  gemm_big<1><<<dim3(768), 512, 0, stream>>>(hsb, wqb, bq, qb);
  gemm_bt<1><<<dim3(12, 10), 256, 0, stream>>>(ehsb, wkb, bk, kgb, 1232, 1536);
  gemm_bt<2><<<dim3(12, 10), 256, 0, stream>>>(ehsb, wvb, bv, vtb, 1232, 1536);

  attn_kernel<<<dim3(64, 24, 2), 256, 0, stream>>>(qb, kgb, vtb, atb);

  gemm_big<0><<<dim3(768), 512, 0, stream>>>(atb, wob, bo, out);
}